// Round 1
// 677.845 us; speedup vs baseline: 1.0844x; 1.0844x over previous
//
#include <hip/hip_runtime.h>
#include <math.h>

#define IMG 64
#define NPX 4096   // IMG*IMG
#define NC  16

typedef float v4f __attribute__((ext_vector_type(4)));

// ---------------------------------------------------------------------------
// Repack OIHW conv weights to [ci*25+tap][co] so the inner co-run is 16
// contiguous floats at a wave-uniform address -> s_load_dwordx16.
// wl0: 400 floats, wl1/wl2: 6400 floats each.
// ---------------------------------------------------------------------------
__global__ void repack_kernel(const float* __restrict__ w0,
                              const float* __restrict__ w1,
                              const float* __restrict__ w2,
                              float* __restrict__ wl0,
                              float* __restrict__ wl1,
                              float* __restrict__ wl2) {
    int idx = blockIdx.x * 256 + threadIdx.x;
    if (idx < 400) {
        int tap = idx >> 4, co = idx & 15;
        wl0[idx] = w0[co * 25 + tap];
    } else if (idx < 6800) {
        int e = idx - 400;
        int k = e >> 4, co = e & 15;          // k = ci*25 + tap
        wl1[e] = w1[co * 400 + k];
    } else if (idx < 13200) {
        int e = idx - 6800;
        int k = e >> 4, co = e & 15;
        wl2[e] = w2[co * 400 + k];
    }
}

// ---------------------------------------------------------------------------
// conv0: 1 input channel -> 16 output channels, 'same' 5x5.
// grid (32 strips, 8 batch), 128 threads; each thread = 1 pixel, 16 co.
// Output layout y0[b][co][p] (channel-first, matches coupling needs).
// ---------------------------------------------------------------------------
__global__ void conv0_kernel(const float* __restrict__ x,   // [8][4096]
                             const float* __restrict__ wl0, // [25][16]
                             const float* __restrict__ b0,  // [16]
                             float* __restrict__ y0) {      // [8][16][4096]
    __shared__ float tile[6 * 68];
    const int strip = blockIdx.x, b = blockIdx.y;
    const int r0 = strip * 2;
    const int tid = threadIdx.x;
    for (int f = tid; f < 6 * 68; f += 128) {
        int row = f / 68, col = f - row * 68;
        int gr = r0 - 2 + row, gc = col - 2;
        float v = 0.f;
        if (gr >= 0 && gr < IMG && gc >= 0 && gc < IMG)
            v = x[b * NPX + gr * IMG + gc];
        tile[f] = v;
    }
    __syncthreads();
    const int ri = tid >> 6, col = tid & 63;
    float acc[16];
#pragma unroll
    for (int co = 0; co < 16; ++co) acc[co] = b0[co];
#pragma unroll
    for (int kh = 0; kh < 5; ++kh) {
        float v[5];
#pragma unroll
        for (int kw = 0; kw < 5; ++kw) v[kw] = tile[(ri + kh) * 68 + col + kw];
#pragma unroll
        for (int kw = 0; kw < 5; ++kw) {
#pragma unroll
            for (int co = 0; co < 16; ++co)
                acc[co] = fmaf(wl0[(kh * 5 + kw) * 16 + co], v[kw], acc[co]);
        }
    }
    const int p = (r0 + ri) * IMG + col;
#pragma unroll
    for (int co = 0; co < 16; ++co)
        y0[(b * 16 + co) * NPX + p] = acc[co];
}

// ---------------------------------------------------------------------------
// conv16: 16 -> 16 channels, 'same' 5x5. grid (32,8), 128 threads.
// DO_STATS=true: fused epilogue computes per-pixel channel mean/std(ddof=1)
// and stores z[c] = (y[c]-m) / (s*sqrt(16))  -> coupling = z_i . z_j * mask.
// Weights read at wave-uniform addresses -> SGPR loads, no LDS/VALU cost.
// ---------------------------------------------------------------------------
template <bool DO_STATS>
__global__ void conv16_kernel(const float* __restrict__ yin,  // [8][16][4096]
                              const float* __restrict__ wl,   // [400][16]
                              const float* __restrict__ bias, // [16]
                              float* __restrict__ yout) {     // [8][16][4096]
    __shared__ float tile[16 * 6 * 68];  // [ci][row][col], cols conflict-free
    const int strip = blockIdx.x, b = blockIdx.y;
    const int r0 = strip * 2;
    const int tid = threadIdx.x;
    for (int f = tid; f < 16 * 408; f += 128) {
        int ci = f / 408;
        int rem = f - ci * 408;
        int row = rem / 68, col = rem - row * 68;
        int gr = r0 - 2 + row, gc = col - 2;
        float v = 0.f;
        if (gr >= 0 && gr < IMG && gc >= 0 && gc < IMG)
            v = yin[(b * 16 + ci) * NPX + gr * IMG + gc];
        tile[f] = v;
    }
    __syncthreads();
    const int ri = tid >> 6, col = tid & 63;
    float acc[16];
#pragma unroll
    for (int co = 0; co < 16; ++co) acc[co] = bias[co];
    for (int ci = 0; ci < 16; ++ci) {
        const float* tci = &tile[ci * 408];
        const float* wci = &wl[ci * 25 * 16];
#pragma unroll
        for (int kh = 0; kh < 5; ++kh) {
            float v[5];
#pragma unroll
            for (int kw = 0; kw < 5; ++kw) v[kw] = tci[(ri + kh) * 68 + col + kw];
#pragma unroll
            for (int kw = 0; kw < 5; ++kw) {
#pragma unroll
                for (int co = 0; co < 16; ++co)
                    acc[co] = fmaf(wci[(kh * 5 + kw) * 16 + co], v[kw], acc[co]);
            }
        }
    }
    const int p = (r0 + ri) * IMG + col;
    if (DO_STATS) {
        float m = 0.f;
#pragma unroll
        for (int co = 0; co < 16; ++co) m += acc[co];
        m *= (1.f / 16.f);
        float var = 0.f;
#pragma unroll
        for (int co = 0; co < 16; ++co) {
            float d = acc[co] - m;
            var = fmaf(d, d, var);
        }
        var *= (1.f / 15.f);                 // unbiased (torch.std / ddof=1)
        float inv = 0.25f / sqrtf(var);      // 1/(s*sqrt(C)), sqrt(16)=4
#pragma unroll
        for (int co = 0; co < 16; ++co)
            yout[(b * 16 + co) * NPX + p] = (acc[co] - m) * inv;
    } else {
#pragma unroll
        for (int co = 0; co < 16; ++co)
            yout[(b * 16 + co) * NPX + p] = acc[co];
    }
}

// ---------------------------------------------------------------------------
// coupling v2: out[b,i,j] = (sum_c z[b,c,i]*z[b,c,j]) * mask[i,j]
// Tile = 256 i-rows x 256 j-cols x all 8 batches. Grid (16,16) = 256 blocks
// = exactly 1 block/CU; 512 threads (8 waves).
//
// Traffic design (the whole point — old B_i=16 version re-read mask 8x and
// zj 256x => ~1.5 GB HBM; roofline is 606 MB):
//   - zj tile [8][16][256] staged ONCE into 128 KiB LDS (m201-proven size).
//   - mask read EXACTLY ONCE per element into regs (8 v4f per i-group),
//     reused across all 8 batches.
//   - zi is wave-uniform (tid>>6 readfirstlane'd) -> scalar loads on the
//     2 MB L2-hot z.
//   - stores nontemporal (537 MB stream must not evict z/mask in L2).
// Inner loop per (i-group, b): 16 ds_read_b128 (192 cyc) vs 512 v_fma
// (1024 cyc) -> VALU-dominant, ~27 us total compute vs ~100 us memory floor.
// ---------------------------------------------------------------------------
__global__ __launch_bounds__(512) void coupling_kernel(
        const float* __restrict__ z,    // [8][16][4096]
        const float* __restrict__ mask, // [4096][4096]
        float* __restrict__ out) {      // [8][4096][4096]
    __shared__ float zj_lds[8 * 16 * 256];   // 128 KiB
    const int tid = threadIdx.x;
    const int j0 = blockIdx.x * 256;
    const int i0 = blockIdx.y * 256;

    // stage z[:, :, j0:j0+256] -> zj_lds[b][c][jj]; 16 iters, fully coalesced
    for (int f = tid; f < 8 * 16 * 64; f += 512) {
        int jq = f & 63;
        int bc = f >> 6;                     // b*16 + c
        v4f v = *(const v4f*)&z[(size_t)bc * NPX + j0 + jq * 4];
        *(v4f*)&zj_lds[bc * 256 + jq * 4] = v;
    }
    __syncthreads();

    const int jq4 = (tid & 63) * 4;                              // j within tile
    const int ir = __builtin_amdgcn_readfirstlane(tid >> 6);     // 0..7, uniform
    // each wave owns 32 i-rows (ir*32..+31), processed as 4 groups of 8
#pragma unroll 1
    for (int g = 0; g < 4; ++g) {
        const int iiB = ir * 32 + g * 8;     // local row base
        v4f mv[8];
#pragma unroll
        for (int k = 0; k < 8; ++k)
            mv[k] = *(const v4f*)&mask[(size_t)(i0 + iiB + k) * NPX + j0 + jq4];
#pragma unroll 1
        for (int b = 0; b < 8; ++b) {
            const float* zi = z + (size_t)(b * 16) * NPX + i0 + iiB;
            v4f acc[8];
#pragma unroll
            for (int k = 0; k < 8; ++k) acc[k] = (v4f)(0.f);
#pragma unroll
            for (int c = 0; c < 16; ++c) {
                v4f zjv = *(const v4f*)&zj_lds[(b * 16 + c) * 256 + jq4];
                const float* zr = zi + c * NPX;  // 8 uniform scalars -> s_load
#pragma unroll
                for (int k = 0; k < 8; ++k)
                    acc[k] += zjv * zr[k];
            }
#pragma unroll
            for (int k = 0; k < 8; ++k) {
                v4f r = acc[k] * mv[k];
                __builtin_nontemporal_store(r,
                    (v4f*)&out[(size_t)(b * NPX + i0 + iiB + k) * NPX + j0 + jq4]);
            }
        }
    }
}

extern "C" void kernel_launch(void* const* d_in, const int* in_sizes, int n_in,
                              void* d_out, int out_size, void* d_ws, size_t ws_size,
                              hipStream_t stream) {
    const float* x    = (const float*)d_in[0];
    const float* w0   = (const float*)d_in[1];
    const float* b0   = (const float*)d_in[2];
    const float* w1   = (const float*)d_in[3];
    const float* b1   = (const float*)d_in[4];
    const float* w2   = (const float*)d_in[5];
    const float* b2   = (const float*)d_in[6];
    const float* mask = (const float*)d_in[7];
    float* out = (float*)d_out;
    float* ws  = (float*)d_ws;

    // workspace layout (floats), 4KB-aligned chunks; total ~6.4 MB
    float* wl0 = ws;                       // 400   (padded to 1024)
    float* wl1 = ws + 1024;                // 6400
    float* wl2 = ws + 8192;                // 6400  (padded to 16384 total)
    float* y0  = ws + 16384;               // 8*16*4096 = 524288
    float* y1  = y0 + 524288;
    float* zz  = y1 + 524288;

    repack_kernel<<<52, 256, 0, stream>>>(w0, w1, w2, wl0, wl1, wl2);
    conv0_kernel<<<dim3(32, 8), 128, 0, stream>>>(x, wl0, b0, y0);
    conv16_kernel<false><<<dim3(32, 8), 128, 0, stream>>>(y0, wl1, b1, y1);
    conv16_kernel<true><<<dim3(32, 8), 128, 0, stream>>>(y1, wl2, b2, zz);
    coupling_kernel<<<dim3(16, 16), 512, 0, stream>>>(zz, mask, out);
}